// Round 8
// baseline (1204.974 us; speedup 1.0000x reference)
//
#include <hip/hip_runtime.h>

#define TS 32
#define NN 1024
#define FF 64
#define HH 128
#define H4 512
#define KC 384    // 3*HH
#define NBLK 64   // blocks per direction
#define FRM (HH * NN) // one hT frame (shorts)
#define ASTR 1032 // adjT row stride (shorts): 2064 B = 129*16B (odd) -> 16B-aligned rows,
                  // (l16+quad) mod 8 uniform bank-group spread for ds_read_b128

typedef __attribute__((ext_vector_type(8))) short bf16x8;
typedef __attribute__((ext_vector_type(4))) float f32x4;
typedef __attribute__((ext_vector_type(4))) short s16x4;

static __device__ __forceinline__ float bf2f(short s) {
    union { unsigned int u; float f; } v;
    v.u = ((unsigned int)(unsigned short)s) << 16;
    return v.f;
}
static __device__ __forceinline__ short f2bf(float x) {   // RTNE
    union { float f; unsigned int u; } v; v.f = x;
    unsigned int r = v.u + 0x7fffu + ((v.u >> 16) & 1u);
    return (short)(r >> 16);
}
static __device__ __forceinline__ bf16x8 cvt8(const float* p) {
    f32x4 lo = *(const f32x4*)p;
    f32x4 hi = *(const f32x4*)(p + 4);
    bf16x8 r;
#pragma unroll
    for (int j = 0; j < 4; j++) { r[j] = f2bf(lo[j]); r[4 + j] = f2bf(hi[j]); }
    return r;
}
static __device__ __forceinline__ bf16x8 cvt8v(f32x4 lo, f32x4 hi) {
    bf16x8 r;
#pragma unroll
    for (int j = 0; j < 4; j++) { r[j] = f2bf(lo[j]); r[4 + j] = f2bf(hi[j]); }
    return r;
}
// non-temporal 16B load: adjs is single-use streaming data -- keeps weights/xs/hT
// cache-resident (round-2 verified: weight HBM re-fetch vanished with NT adj)
static __device__ __forceinline__ f32x4 ldnt4(const float* p) {
    return __builtin_nontemporal_load((const f32x4*)p);
}
// fast reciprocal (round-7 verified: VALUBusy 6.97 -> 4.41%)
static __device__ __forceinline__ float frcp(float x) {
    float r; asm("v_rcp_f32 %0, %1" : "=v"(r) : "v"(x)); return r;
}
static __device__ __forceinline__ float sigm(float x) { return frcp(1.0f + __expf(-x)); }
static __device__ __forceinline__ float tanhfast(float x) { return 1.0f - 2.0f * frcp(__expf(2.0f * x) + 1.0f); }
static __device__ __forceinline__ f32x4 MFMA(bf16x8 a, bf16x8 b, f32x4 c) {
    return __builtin_amdgcn_mfma_f32_16x16x32_bf16(a, b, c, 0, 0, 0);
}
// MFMA with B-operand pinned in AGPRs (gfx950 unified file: MFMA src may be AGPR).
// This is how the 144-reg i/f/o weight set becomes register-resident DESPITE the
// allocator's empirical 128-arch-VGPR cap (rounds 1/2/6): AGPRs are a separate
// half of the unified file that plain HIP codegen never touches in this kernel.
static __device__ __forceinline__ void MFMA_AB(f32x4& c, bf16x8 a, bf16x8 b_agpr) {
    asm("v_mfma_f32_16x16x32_bf16 %0, %1, %2, %0"
        : "+v"(c) : "v"(a), "a"(b_agpr));
}

// ---- fused prologue: xs-GEMM (blocks 0..511), weight transpose (512..607),
// ---- fc0/wout fold + flag/out zero (block 608)
__global__ __launch_bounds__(256) void k_pre(
    const float* __restrict__ x, const float* __restrict__ winw,
    const float* __restrict__ winb,
    const float* __restrict__ fWx, const float* __restrict__ fWn,
    const float* __restrict__ fWh,
    const float* __restrict__ bWx, const float* __restrict__ bWn,
    const float* __restrict__ bWh,
    const float* __restrict__ fc0_w, const float* __restrict__ fc0_b,
    const float* __restrict__ wout_w, const float* __restrict__ wout_b,
    short* __restrict__ xs, short* __restrict__ hTf0, short* __restrict__ hTb0,
    short* __restrict__ WcatT_f, short* __restrict__ WcatT_b,
    float* __restrict__ vsh_g, unsigned int* __restrict__ flags,
    float* __restrict__ out) {
    const int b = blockIdx.x;
    const int tid = threadIdx.x;
    if (b < 512) {
        // xs = x @ Win^T + b; also init transposed h carries for frames 0 / T-1
        const int wv = tid >> 6, lane = tid & 63;
        const int quad = lane >> 4, l16 = lane & 15;
        const int row0 = b * 64 + wv * 16;
        f32x4 acc[8];
#pragma unroll
        for (int i = 0; i < 8; i++) acc[i] = (f32x4){0.f, 0.f, 0.f, 0.f};
#pragma unroll
        for (int kt = 0; kt < 2; kt++) {
            const int k = kt * 32 + quad * 8;
            bf16x8 a = cvt8(x + (size_t)(row0 + l16) * FF + k);
#pragma unroll
            for (int nt = 0; nt < 8; nt++) {
                bf16x8 bb = cvt8(winw + (size_t)(nt * 16 + l16) * FF + k);
                acc[nt] = MFMA(a, bb, acc[nt]);
            }
        }
#pragma unroll
        for (int nt = 0; nt < 8; nt++) {
            const int hcol = nt * 16 + l16;
            const float bias = winb[hcol];
#pragma unroll
            for (int r = 0; r < 4; r++) {
                const int row = row0 + quad * 4 + r;
                const short v = f2bf(acc[nt][r] + bias);
                xs[(size_t)row * HH + hcol] = v;
                const int frame = row >> 10, nrow = row & 1023;
                if (frame == 0) hTf0[(size_t)hcol * NN + nrow] = v;
                else if (frame == TS - 1) hTb0[(size_t)hcol * NN + nrow] = v;
            }
        }
    } else if (b < 608) {
        __shared__ __align__(16) short tile[64][72];
        const int b2 = b - 512;
        const int half = b2 / 48, sub = b2 % 48;
        const float* Wx = half ? bWx : fWx;
        const float* Wn = half ? bWn : fWn;
        const float* Wh = half ? bWh : fWh;
        short* dst = half ? WcatT_b : WcatT_f;
        const int n0 = (sub / 6) * 64, k0 = (sub % 6) * 64;
        for (int i = tid; i < 512; i += 256) {
            const int r = i >> 3, cc = i & 7;
            const int kg = k0 + r;
            const float* m = (kg < 128) ? Wx : (kg < 256 ? Wn : Wh);
            *(bf16x8*)&tile[r][cc * 8] = cvt8(m + (size_t)(kg & 127) * H4 + n0 + cc * 8);
        }
        __syncthreads();
        for (int i = tid; i < 512; i += 256) {
            const int rr = i >> 3, kk = i & 7;
            bf16x8 o;
#pragma unroll
            for (int j = 0; j < 8; j++) o[j] = tile[kk * 8 + j][rr];
            *(bf16x8*)(dst + (size_t)(n0 + rr) * KC + k0 + kk * 8) = o;
        }
    } else {
        // v[j] = sum_i wout_w[i]*fc0_w[i*256+j]; s0 = wout_b + wout_w . fc0_b
        float a = 0.f;
        for (int i = 0; i < HH; i++) a += wout_w[i] * fc0_w[(size_t)i * 256 + tid];
        vsh_g[tid] = a;
        if (tid == 0) {
            float s = wout_b[0];
            for (int i = 0; i < HH; i++) s += wout_w[i] * fc0_b[i];
            vsh_g[256] = s;
        }
        for (int i = tid; i < 128; i += 256) flags[i] = 0u;
        for (int i = tid; i < NN; i += 256) out[i] = 0.f;
    }
}

// ---- persistent main kernel: 128 blocks x 512 thr, block = (dir, 16 rows) --------
// Round-8 = round-7 + AGPR-resident i/f/o weights. The 576 KB/block-step weight
// re-stream (36 frags x 16B x 2 layers x 8 waves, the ~160 MB of non-adj HBM FETCH)
// moves into 144 AGPRs consumed directly by inline-asm MFMA. G/H inner loop now
// has zero global loads. Budget: ~110 VGPR + 144 AGPR = ~254 <= 256/wave at
// 2 waves/SIMD (occupancy unchanged -- verify OccupancyPercent stays ~12).
__global__ __launch_bounds__(512)
__attribute__((amdgpu_waves_per_eu(2, 2))) void k_main(
    const float* __restrict__ adjs, const short* __restrict__ xs,
    const short* __restrict__ WcT_f, const short* __restrict__ WcT_b,
    const float* __restrict__ bias_f, const float* __restrict__ bias_b,
    short* __restrict__ hTf, short* __restrict__ hTb,
    const float* __restrict__ vsh_g, unsigned int* __restrict__ flags,
    float* __restrict__ out) {
    __shared__ __align__(16) short wg[12 * 4 * HH * 8];   // gate-g weights, 96 KB
    __shared__ __align__(16) short adjT[16 * ASTR];       // ~33 KB, conflict-free
    __shared__ __align__(16) short Acat[16][392];         // [xs | n | h]

    const int tid = threadIdx.x;
    const int wv = tid >> 6, lane = tid & 63, quad = lane >> 4, l16 = lane & 15;
    const int dir = blockIdx.x >> 6, bslot = blockIdx.x & 63, R = bslot * 16;
    const short* WcT  = dir ? WcT_b : WcT_f;
    const float* bias = dir ? bias_b : bias_f;
    short* hTd = dir ? hTb : hTf;
    unsigned int* myflags = flags + dir * 64;
    const int hcol = wv * 16 + l16;

    // gates i,f,o fragments -> AGPRs (loaded once, pinned; all uses are "a"-
    // constrained asm MFMA, so the allocator keeps them in the acc half of the
    // unified file, away from the 128-arch-VGPR cap)
    bf16x8 wr0[12], wr1[12], wr2[12];
#pragma unroll
    for (int kt = 0; kt < 12; kt++) {
        wr0[kt] = *(const bf16x8*)(WcT + (size_t)(0 * HH + hcol) * KC + kt * 32 + quad * 8);
        wr1[kt] = *(const bf16x8*)(WcT + (size_t)(1 * HH + hcol) * KC + kt * 32 + quad * 8);
        wr2[kt] = *(const bf16x8*)(WcT + (size_t)(2 * HH + hcol) * KC + kt * 32 + quad * 8);
        asm("" : "+a"(wr0[kt]), "+a"(wr1[kt]), "+a"(wr2[kt]));
    }
    // gate g in LDS: [kt][quad][hcol] bf16x8 granules
    for (int i = tid; i < 6144; i += 512) {
        const int kt = i >> 9, rem = i & 511, qd = rem >> 7, hc = rem & 127;
        *(bf16x8*)&wg[(size_t)i * 8] =
            *(const bf16x8*)(WcT + (size_t)(3 * HH + hc) * KC + kt * 32 + qd * 8);
    }
    const float bi  = bias[hcol];
    const float bf_ = bias[HH + hcol];
    const float bo  = bias[2 * HH + hcol];
    const float bg_ = bias[3 * HH + hcol];

    const int frame0 = dir ? (TS - 1) : 0;
    if (tid < 256) {
        const int r = tid >> 4, cc = tid & 15;
        *(bf16x8*)&Acat[r][256 + cc * 8] =
            *(const bf16x8*)(xs + ((size_t)frame0 * NN + R + r) * HH + cc * 8);
    }
    // prologue: stage adjT(frame0). lane map: row=tid&15, colgroup=tid>>4 (bank-clean)
    const int ar = tid & 15, ac = tid >> 4;
    {
        const float* asrc = adjs + (size_t)frame0 * NN * NN + (size_t)(R + ar) * NN + ac * 32;
        f32x4 p0[8];
#pragma unroll
        for (int j = 0; j < 8; j++) p0[j] = ldnt4(asrc + j * 4);
#pragma unroll
        for (int j = 0; j < 4; j++)
            *(bf16x8*)&adjT[ar * ASTR + ac * 32 + j * 8] = cvt8v(p0[2 * j], p0[2 * j + 1]);
    }
    __syncthreads();
    float creg[4];
#pragma unroll
    for (int r = 0; r < 4; r++) creg[r] = bf2f(Acat[quad * 4 + r][256 + hcol]);

    f32x4 pf[8];
    for (int t = 0; t < TS; t++) {
        const int frame = dir ? (TS - 1 - t) : t;
        const short* xs_t = xs + (size_t)frame * NN * HH;
        const short* hTi = hTd + (size_t)t * FRM;        // read frame t (fresh, cacheable)
        short* hTo       = hTd + (size_t)(t + 1) * FRM;  // write frame t+1 (to LLC)

        // A: stage xs_t rows (first reader is G, after the E barrier)
        if (tid < 256) {
            const int r = tid >> 4, cc = tid & 15;
            *(bf16x8*)&Acat[r][cc * 8] =
                *(const bf16x8*)(xs_t + (size_t)(R + r) * HH + cc * 8);
        }
        // B: prefetch next frame's adj rows into registers, non-temporal
        if (t < TS - 1) {
            const int nf = dir ? (TS - 2 - t) : (t + 1);
            const float* asrc = adjs + (size_t)nf * NN * NN + (size_t)(R + ar) * NN + ac * 32;
#pragma unroll
            for (int j = 0; j < 8; j++) pf[j] = ldnt4(asrc + j * 4);
        }
        // C: per-wave spin (round-7 verified): every wave polls all 64 slots with
        //    one coalesced 256B load per trip, proceeds on observation.
        {
            unsigned int v;
            do {
                v = __hip_atomic_load(myflags + lane, __ATOMIC_RELAXED,
                                      __HIP_MEMORY_SCOPE_AGENT);
            } while (__ballot(v < (unsigned int)t) != 0ull);
        }
        asm volatile("" ::: "memory");

        // D: n = adj_rows @ h_time. Plain cached b128 loads of frame t (cold
        //    lines fill this XCD's L2 once from LLC; same-dir blocks share).
        f32x4 an0 = (f32x4){0.f, 0.f, 0.f, 0.f};
        f32x4 an1 = (f32x4){0.f, 0.f, 0.f, 0.f};
        const short* hrow = hTi + (size_t)hcol * NN;
#pragma unroll
        for (int kt = 0; kt < 32; kt += 2) {
            bf16x8 a0 = *(const bf16x8*)&adjT[l16 * ASTR + kt * 32 + quad * 8];
            bf16x8 b0 = *(const bf16x8*)(hrow + kt * 32 + quad * 8);
            an0 = MFMA(a0, b0, an0);
            bf16x8 a1 = *(const bf16x8*)&adjT[l16 * ASTR + (kt + 1) * 32 + quad * 8];
            bf16x8 b1 = *(const bf16x8*)(hrow + (kt + 1) * 32 + quad * 8);
            an1 = MFMA(a1, b1, an1);
        }
#pragma unroll
        for (int r = 0; r < 4; r++) Acat[quad * 4 + r][HH + hcol] = f2bf(an0[r] + an1[r]);
        __syncthreads();   // E: n visible; all phase-D adjT reads done; A visible

        // F: write next step's adjT from prefetched regs
        if (t < TS - 1) {
#pragma unroll
            for (int j = 0; j < 4; j++)
                *(bf16x8*)&adjT[ar * ASTR + ac * 32 + j * 8] = cvt8v(pf[2 * j], pf[2 * j + 1]);
        }

        // G/H: two GNN layers -- zero global loads in the loop (i/f/o from AGPR,
        //    g from LDS, activations from LDS)
#pragma unroll
        for (int l = 0; l < 2; l++) {
            f32x4 az0 = (f32x4){0.f, 0.f, 0.f, 0.f};
            f32x4 az1 = az0, az2 = az0, az3 = az0;
#pragma unroll
            for (int kt = 0; kt < 12; kt++) {
                bf16x8 a = *(const bf16x8*)&Acat[l16][kt * 32 + quad * 8];
                MFMA_AB(az0, a, wr0[kt]);
                MFMA_AB(az1, a, wr1[kt]);
                MFMA_AB(az2, a, wr2[kt]);
                bf16x8 b3 = *(const bf16x8*)&wg[((size_t)kt * 512 + quad * 128 + hcol) * 8];
                az3 = MFMA(a, b3, az3);
            }
            // hazard guard: the compiler cannot see the asm MFMAs' write->VALU-read
            // latency; 16 wait states cover the MAI pipeline depth.
            asm volatile("s_nop 7\n\ts_nop 7" :::);
            short hbf[4];
#pragma unroll
            for (int r = 0; r < 4; r++) {
                const float cn = sigm(az1[r] + bf_) * creg[r]
                               + sigm(az0[r] + bi) * tanhfast(az3[r] + bg_);
                creg[r] = cn;
                hbf[r] = f2bf(sigm(az2[r] + bo) * tanhfast(cn));
            }
            // layer-2 global publish into frame t+1 (agent-scope so it lands at
            // LLC, visible to other XCDs' cold fills); overlaps the LDS epilogue
            if (l == 1) {
                union { s16x4 v; unsigned long long u; } pk;
#pragma unroll
                for (int r = 0; r < 4; r++) pk.v[r] = hbf[r];
                __hip_atomic_store(
                    (unsigned long long*)(hTo + (size_t)hcol * NN + R + quad * 4),
                    pk.u, __ATOMIC_RELAXED, __HIP_MEMORY_SCOPE_AGENT);
            }
            __syncthreads();   // all waves done reading Acat h-region
#pragma unroll
            for (int r = 0; r < 4; r++) Acat[quad * 4 + r][256 + hcol] = hbf[r];
            if (l == 0) __syncthreads();
        }
        // I: arrive -- own h stores acked at LLC (vmcnt0), block-joined, then one
        //    release store into this block's OWN flag slot
        asm volatile("s_waitcnt vmcnt(0)" ::: "memory");
        __syncthreads();
        if (tid == 0)
            __hip_atomic_store(myflags + bslot, (unsigned int)(t + 1),
                               __ATOMIC_RELEASE, __HIP_MEMORY_SCOPE_AGENT);
    }

    // epilogue: each dir contributes its half of y via f32 atomicAdd (out zeroed)
    if (tid < 256) {
        const int r = tid >> 4, j = tid & 15;
        float p = 0.f;
        for (int k = j * 8; k < j * 8 + 8; k++)
            p += bf2f(Acat[r][256 + k]) * vsh_g[dir * HH + k];
#pragma unroll
        for (int off = 8; off; off >>= 1) p += __shfl_down(p, off, 16);
        if (j == 0) atomicAdd(&out[R + r], p + (dir ? 0.f : vsh_g[256]));
    }
}

extern "C" void kernel_launch(void* const* d_in, const int* in_sizes, int n_in,
                              void* d_out, int out_size, void* d_ws, size_t ws_size,
                              hipStream_t stream) {
    const float* x      = (const float*)d_in[0];
    const float* adjs   = (const float*)d_in[1];
    const float* win_w  = (const float*)d_in[3];
    const float* win_b  = (const float*)d_in[4];
    const float* fWx    = (const float*)d_in[5];
    const float* fWh    = (const float*)d_in[6];
    const float* fWn    = (const float*)d_in[7];
    const float* fb     = (const float*)d_in[8];
    const float* bWx    = (const float*)d_in[9];
    const float* bWh    = (const float*)d_in[10];
    const float* bWn    = (const float*)d_in[11];
    const float* bb     = (const float*)d_in[12];
    const float* fc0_w  = (const float*)d_in[13];
    const float* fc0_b  = (const float*)d_in[14];
    const float* wout_w = (const float*)d_in[15];
    const float* wout_b = (const float*)d_in[16];

    char* ws = (char*)d_ws;
    size_t off = 0;
    auto alloc = [&](size_t bytes) -> void* {
        void* p = ws + off;
        off += (bytes + 255) & ~(size_t)255;
        return p;
    };
    short* xs      = (short*)alloc((size_t)TS * NN * HH * 2);
    short* WcatT_f = (short*)alloc((size_t)H4 * KC * 2);
    short* WcatT_b = (short*)alloc((size_t)H4 * KC * 2);
    // 33-deep hT frame chains (write-once/read-once -> no stale-L2 hazard)
    short* hTf     = (short*)alloc((size_t)(TS + 1) * FRM * 2);
    short* hTb     = (short*)alloc((size_t)(TS + 1) * FRM * 2);
    float* vsh_g   = (float*)alloc(257 * 4);
    unsigned int* flags = (unsigned int*)alloc(512);
    float* outp    = (float*)d_out;

    hipLaunchKernelGGL(k_pre, dim3(609), dim3(256), 0, stream,
                       x, win_w, win_b, fWx, fWn, fWh, bWx, bWn, bWh,
                       fc0_w, fc0_b, wout_w, wout_b,
                       xs, hTf, hTb, WcatT_f, WcatT_b, vsh_g, flags, outp);

    void* args[] = {
        (void*)&adjs, (void*)&xs, (void*)&WcatT_f, (void*)&WcatT_b,
        (void*)&fb, (void*)&bb,
        (void*)&hTf, (void*)&hTb,
        (void*)&vsh_g, (void*)&flags, (void*)&outp,
    };
    hipLaunchCooperativeKernel((void*)k_main, dim3(128), dim3(512), args, 0, stream);
}

// Round 9
// 897.584 us; speedup vs baseline: 1.3425x; 1.3425x over previous
//
#include <hip/hip_runtime.h>

#define TS 32
#define NN 1024
#define FF 64
#define HH 128
#define H4 512
#define KC 384    // 3*HH
#define NBLK 64   // blocks per direction
#define FRM (HH * NN) // one hT frame (shorts)
#define ASTR 1032 // adjT row stride (shorts): 2064 B = 129*16B (odd) -> 16B-aligned rows,
                  // (l16+quad) mod 8 uniform bank-group spread for ds_read_b128

typedef __attribute__((ext_vector_type(8))) short bf16x8;
typedef __attribute__((ext_vector_type(4))) float f32x4;
typedef __attribute__((ext_vector_type(4))) short s16x4;

static __device__ __forceinline__ float bf2f(short s) {
    union { unsigned int u; float f; } v;
    v.u = ((unsigned int)(unsigned short)s) << 16;
    return v.f;
}
static __device__ __forceinline__ short f2bf(float x) {   // RTNE
    union { float f; unsigned int u; } v; v.f = x;
    unsigned int r = v.u + 0x7fffu + ((v.u >> 16) & 1u);
    return (short)(r >> 16);
}
static __device__ __forceinline__ bf16x8 cvt8(const float* p) {
    f32x4 lo = *(const f32x4*)p;
    f32x4 hi = *(const f32x4*)(p + 4);
    bf16x8 r;
#pragma unroll
    for (int j = 0; j < 4; j++) { r[j] = f2bf(lo[j]); r[4 + j] = f2bf(hi[j]); }
    return r;
}
static __device__ __forceinline__ bf16x8 cvt8v(f32x4 lo, f32x4 hi) {
    bf16x8 r;
#pragma unroll
    for (int j = 0; j < 4; j++) { r[j] = f2bf(lo[j]); r[4 + j] = f2bf(hi[j]); }
    return r;
}
// non-temporal 16B load: adjs is single-use-per-direction streaming data
static __device__ __forceinline__ f32x4 ldnt4(const float* p) {
    return __builtin_nontemporal_load((const f32x4*)p);
}
// fast reciprocal (round-7 verified: VALUBusy 6.97 -> 4.41%, -23 us)
static __device__ __forceinline__ float frcp(float x) {
    float r; asm("v_rcp_f32 %0, %1" : "=v"(r) : "v"(x)); return r;
}
static __device__ __forceinline__ float sigm(float x) { return frcp(1.0f + __expf(-x)); }
static __device__ __forceinline__ float tanhfast(float x) { return 1.0f - 2.0f * frcp(__expf(2.0f * x) + 1.0f); }
static __device__ __forceinline__ f32x4 MFMA(bf16x8 a, bf16x8 b, f32x4 c) {
    return __builtin_amdgcn_mfma_f32_16x16x32_bf16(a, b, c, 0, 0, 0);
}

// ---- fused prologue: xs-GEMM (blocks 0..511), weight transpose (512..607),
// ---- fc0/wout fold + flag/out zero (block 608)
__global__ __launch_bounds__(256) void k_pre(
    const float* __restrict__ x, const float* __restrict__ winw,
    const float* __restrict__ winb,
    const float* __restrict__ fWx, const float* __restrict__ fWn,
    const float* __restrict__ fWh,
    const float* __restrict__ bWx, const float* __restrict__ bWn,
    const float* __restrict__ bWh,
    const float* __restrict__ fc0_w, const float* __restrict__ fc0_b,
    const float* __restrict__ wout_w, const float* __restrict__ wout_b,
    short* __restrict__ xs, short* __restrict__ hTf0, short* __restrict__ hTb0,
    short* __restrict__ WcatT_f, short* __restrict__ WcatT_b,
    float* __restrict__ vsh_g, unsigned int* __restrict__ flags,
    float* __restrict__ out) {
    const int b = blockIdx.x;
    const int tid = threadIdx.x;
    if (b < 512) {
        // xs = x @ Win^T + b; also init transposed h carries for frames 0 / T-1
        const int wv = tid >> 6, lane = tid & 63;
        const int quad = lane >> 4, l16 = lane & 15;
        const int row0 = b * 64 + wv * 16;
        f32x4 acc[8];
#pragma unroll
        for (int i = 0; i < 8; i++) acc[i] = (f32x4){0.f, 0.f, 0.f, 0.f};
#pragma unroll
        for (int kt = 0; kt < 2; kt++) {
            const int k = kt * 32 + quad * 8;
            bf16x8 a = cvt8(x + (size_t)(row0 + l16) * FF + k);
#pragma unroll
            for (int nt = 0; nt < 8; nt++) {
                bf16x8 bb = cvt8(winw + (size_t)(nt * 16 + l16) * FF + k);
                acc[nt] = MFMA(a, bb, acc[nt]);
            }
        }
#pragma unroll
        for (int nt = 0; nt < 8; nt++) {
            const int hcol = nt * 16 + l16;
            const float bias = winb[hcol];
#pragma unroll
            for (int r = 0; r < 4; r++) {
                const int row = row0 + quad * 4 + r;
                const short v = f2bf(acc[nt][r] + bias);
                xs[(size_t)row * HH + hcol] = v;
                const int frame = row >> 10, nrow = row & 1023;
                if (frame == 0) hTf0[(size_t)hcol * NN + nrow] = v;
                else if (frame == TS - 1) hTb0[(size_t)hcol * NN + nrow] = v;
            }
        }
    } else if (b < 608) {
        __shared__ __align__(16) short tile[64][72];
        const int b2 = b - 512;
        const int half = b2 / 48, sub = b2 % 48;
        const float* Wx = half ? bWx : fWx;
        const float* Wn = half ? bWn : fWn;
        const float* Wh = half ? bWh : fWh;
        short* dst = half ? WcatT_b : WcatT_f;
        const int n0 = (sub / 6) * 64, k0 = (sub % 6) * 64;
        for (int i = tid; i < 512; i += 256) {
            const int r = i >> 3, cc = i & 7;
            const int kg = k0 + r;
            const float* m = (kg < 128) ? Wx : (kg < 256 ? Wn : Wh);
            *(bf16x8*)&tile[r][cc * 8] = cvt8(m + (size_t)(kg & 127) * H4 + n0 + cc * 8);
        }
        __syncthreads();
        for (int i = tid; i < 512; i += 256) {
            const int rr = i >> 3, kk = i & 7;
            bf16x8 o;
#pragma unroll
            for (int j = 0; j < 8; j++) o[j] = tile[kk * 8 + j][rr];
            *(bf16x8*)(dst + (size_t)(n0 + rr) * KC + k0 + kk * 8) = o;
        }
    } else {
        // v[j] = sum_i wout_w[i]*fc0_w[i*256+j]; s0 = wout_b + wout_w . fc0_b
        float a = 0.f;
        for (int i = 0; i < HH; i++) a += wout_w[i] * fc0_w[(size_t)i * 256 + tid];
        vsh_g[tid] = a;
        if (tid == 0) {
            float s = wout_b[0];
            for (int i = 0; i < HH; i++) s += wout_w[i] * fc0_b[i];
            vsh_g[256] = s;
        }
        for (int i = tid; i < 128; i += 256) flags[i] = 0u;
        for (int i = tid; i < NN; i += 256) out[i] = 0.f;
    }
}

// ---- persistent main kernel: 128 blocks x 512 thr, block = (dir, 16 rows) --------
// Round-9 = round-7 (verified 705 us) with D fused into the wait: each wave polls
// the 64-flag array (one coalesced 256B load) and, as producer GROUPS arrive,
// immediately accumulates their 64-node slice of n = adj @ h. Group = 4 producer
// blocks = 64 nodes = one 128B cacheline per hT row, so no line is read before
// ALL its writers flagged (write-once/read-once L2 safety holds at line
// granularity). By the last straggler's flag, ~15/16 of D is already done and its
// hT loads were serviced during the formerly-idle spin window. Round-8's AGPR
// pinning reverted (144 "a"-regs > the 128 accum slots available at 2 waves/SIMD
// -> total spill, +563 MB FETCH).
__global__ __launch_bounds__(512)
__attribute__((amdgpu_waves_per_eu(2, 2))) void k_main(
    const float* __restrict__ adjs, const short* __restrict__ xs,
    const short* __restrict__ WcT_f, const short* __restrict__ WcT_b,
    const float* __restrict__ bias_f, const float* __restrict__ bias_b,
    short* __restrict__ hTf, short* __restrict__ hTb,
    const float* __restrict__ vsh_g, unsigned int* __restrict__ flags,
    float* __restrict__ out) {
    __shared__ __align__(16) short wg[12 * 4 * HH * 8];   // gate-g weights, 96 KB
    __shared__ __align__(16) short adjT[16 * ASTR];       // ~33 KB, conflict-free
    __shared__ __align__(16) short Acat[16][392];         // [xs | n | h]

    const int tid = threadIdx.x;
    const int wv = tid >> 6, lane = tid & 63, quad = lane >> 4, l16 = lane & 15;
    const int dir = blockIdx.x >> 6, bslot = blockIdx.x & 63, R = bslot * 16;
    const short* WcT  = dir ? WcT_b : WcT_f;
    const float* bias = dir ? bias_b : bias_f;
    short* hTd = dir ? hTb : hTf;
    unsigned int* myflags = flags + dir * 64;
    const int hcol = wv * 16 + l16;

    // gates i,f,o fragments (compiler re-streams from warm L2 per use --
    // round 2 proved that's off the critical path)
    bf16x8 wr0[12], wr1[12], wr2[12];
#pragma unroll
    for (int kt = 0; kt < 12; kt++) {
        wr0[kt] = *(const bf16x8*)(WcT + (size_t)(0 * HH + hcol) * KC + kt * 32 + quad * 8);
        wr1[kt] = *(const bf16x8*)(WcT + (size_t)(1 * HH + hcol) * KC + kt * 32 + quad * 8);
        wr2[kt] = *(const bf16x8*)(WcT + (size_t)(2 * HH + hcol) * KC + kt * 32 + quad * 8);
    }
    // gate g in LDS: [kt][quad][hcol] bf16x8 granules
    for (int i = tid; i < 6144; i += 512) {
        const int kt = i >> 9, rem = i & 511, qd = rem >> 7, hc = rem & 127;
        *(bf16x8*)&wg[(size_t)i * 8] =
            *(const bf16x8*)(WcT + (size_t)(3 * HH + hc) * KC + kt * 32 + qd * 8);
    }
    const float bi  = bias[hcol];
    const float bf_ = bias[HH + hcol];
    const float bo  = bias[2 * HH + hcol];
    const float bg_ = bias[3 * HH + hcol];

    const int frame0 = dir ? (TS - 1) : 0;
    if (tid < 256) {
        const int r = tid >> 4, cc = tid & 15;
        *(bf16x8*)&Acat[r][256 + cc * 8] =
            *(const bf16x8*)(xs + ((size_t)frame0 * NN + R + r) * HH + cc * 8);
    }
    // prologue: stage adjT(frame0). lane map: row=tid&15, colgroup=tid>>4 (bank-clean)
    const int ar = tid & 15, ac = tid >> 4;
    {
        const float* asrc = adjs + (size_t)frame0 * NN * NN + (size_t)(R + ar) * NN + ac * 32;
        f32x4 p0[8];
#pragma unroll
        for (int j = 0; j < 8; j++) p0[j] = ldnt4(asrc + j * 4);
#pragma unroll
        for (int j = 0; j < 4; j++)
            *(bf16x8*)&adjT[ar * ASTR + ac * 32 + j * 8] = cvt8v(p0[2 * j], p0[2 * j + 1]);
    }
    __syncthreads();
    float creg[4];
#pragma unroll
    for (int r = 0; r < 4; r++) creg[r] = bf2f(Acat[quad * 4 + r][256 + hcol]);

    f32x4 pf[8];
    for (int t = 0; t < TS; t++) {
        const int frame = dir ? (TS - 1 - t) : t;
        const short* xs_t = xs + (size_t)frame * NN * HH;
        const short* hTi = hTd + (size_t)t * FRM;        // read frame t (fresh, cacheable)
        short* hTo       = hTd + (size_t)(t + 1) * FRM;  // write frame t+1 (to LLC)

        // A: stage xs_t rows (first reader is G, after the E barrier)
        if (tid < 256) {
            const int r = tid >> 4, cc = tid & 15;
            *(bf16x8*)&Acat[r][cc * 8] =
                *(const bf16x8*)(xs_t + (size_t)(R + r) * HH + cc * 8);
        }
        // B: prefetch next frame's adj rows into registers, non-temporal
        if (t < TS - 1) {
            const int nf = dir ? (TS - 2 - t) : (t + 1);
            const float* asrc = adjs + (size_t)nf * NN * NN + (size_t)(R + ar) * NN + ac * 32;
#pragma unroll
            for (int j = 0; j < 8; j++) pf[j] = ldnt4(asrc + j * 4);
        }

        // C+D fused (incremental D): poll flags; process arrived 4-block groups
        // (64 nodes = 128B line per hT row). HW ordering: chunk loads issue only
        // after the branch on this iteration's flag observation resolves (in-order
        // wave execution, no load speculation past unresolved branches); the
        // compiler barrier pins compile-time order. Two alternating accumulators
        // keep the MFMA dep-chain split exactly as in round 7.
        f32x4 an0 = (f32x4){0.f, 0.f, 0.f, 0.f};
        f32x4 an1 = (f32x4){0.f, 0.f, 0.f, 0.f};
        {
            const short* hbase = hTi + (size_t)hcol * NN;
            const unsigned long long FULL = 0x1111111111111111ull;
            unsigned long long done = 0ull;
            do {
                unsigned int v = __hip_atomic_load(myflags + lane, __ATOMIC_RELAXED,
                                                   __HIP_MEMORY_SCOPE_AGENT);
                unsigned long long arrived = __ballot(v >= (unsigned int)t);
                unsigned long long grp = arrived & (arrived >> 1) & (arrived >> 2)
                                       & (arrived >> 3) & FULL;
                unsigned long long todo = grp & ~done;
                done |= todo;
                asm volatile("" ::: "memory");
                while (todo) {
                    const int b = (int)__ffsll((unsigned long long)todo) - 1;
                    todo &= todo - 1;
                    const int kt = b >> 1;   // b = 4g -> kt = 2g
                    bf16x8 a0 = *(const bf16x8*)&adjT[l16 * ASTR + kt * 32 + quad * 8];
                    bf16x8 b0 = *(const bf16x8*)(hbase + kt * 32 + quad * 8);
                    an0 = MFMA(a0, b0, an0);
                    bf16x8 a1 = *(const bf16x8*)&adjT[l16 * ASTR + (kt + 1) * 32 + quad * 8];
                    bf16x8 b1 = *(const bf16x8*)(hbase + (kt + 1) * 32 + quad * 8);
                    an1 = MFMA(a1, b1, an1);
                }
            } while (done != FULL);
        }
#pragma unroll
        for (int r = 0; r < 4; r++) Acat[quad * 4 + r][HH + hcol] = f2bf(an0[r] + an1[r]);
        __syncthreads();   // E: n visible; all phase-D adjT reads done; A visible

        // F: write next step's adjT from prefetched regs
        if (t < TS - 1) {
#pragma unroll
            for (int j = 0; j < 4; j++)
                *(bf16x8*)&adjT[ar * ASTR + ac * 32 + j * 8] = cvt8v(pf[2 * j], pf[2 * j + 1]);
        }

        // G/H: two GNN layers
#pragma unroll
        for (int l = 0; l < 2; l++) {
            f32x4 az0 = (f32x4){0.f, 0.f, 0.f, 0.f};
            f32x4 az1 = az0, az2 = az0, az3 = az0;
#pragma unroll
            for (int kt = 0; kt < 12; kt++) {
                bf16x8 a = *(const bf16x8*)&Acat[l16][kt * 32 + quad * 8];
                az0 = MFMA(a, wr0[kt], az0);
                az1 = MFMA(a, wr1[kt], az1);
                az2 = MFMA(a, wr2[kt], az2);
                bf16x8 b3 = *(const bf16x8*)&wg[((size_t)kt * 512 + quad * 128 + hcol) * 8];
                az3 = MFMA(a, b3, az3);
            }
            short hbf[4];
#pragma unroll
            for (int r = 0; r < 4; r++) {
                const float cn = sigm(az1[r] + bf_) * creg[r]
                               + sigm(az0[r] + bi) * tanhfast(az3[r] + bg_);
                creg[r] = cn;
                hbf[r] = f2bf(sigm(az2[r] + bo) * tanhfast(cn));
            }
            // layer-2 global publish into frame t+1 (agent-scope so it lands at
            // LLC, visible to other XCDs' cold fills); overlaps the LDS epilogue
            if (l == 1) {
                union { s16x4 v; unsigned long long u; } pk;
#pragma unroll
                for (int r = 0; r < 4; r++) pk.v[r] = hbf[r];
                __hip_atomic_store(
                    (unsigned long long*)(hTo + (size_t)hcol * NN + R + quad * 4),
                    pk.u, __ATOMIC_RELAXED, __HIP_MEMORY_SCOPE_AGENT);
            }
            __syncthreads();   // all waves done reading Acat h-region
#pragma unroll
            for (int r = 0; r < 4; r++) Acat[quad * 4 + r][256 + hcol] = hbf[r];
            if (l == 0) __syncthreads();
        }
        // I: arrive -- own h stores acked at LLC (vmcnt0), block-joined, then one
        //    release store into this block's OWN flag slot
        asm volatile("s_waitcnt vmcnt(0)" ::: "memory");
        __syncthreads();
        if (tid == 0)
            __hip_atomic_store(myflags + bslot, (unsigned int)(t + 1),
                               __ATOMIC_RELEASE, __HIP_MEMORY_SCOPE_AGENT);
    }

    // epilogue: each dir contributes its half of y via f32 atomicAdd (out zeroed)
    if (tid < 256) {
        const int r = tid >> 4, j = tid & 15;
        float p = 0.f;
        for (int k = j * 8; k < j * 8 + 8; k++)
            p += bf2f(Acat[r][256 + k]) * vsh_g[dir * HH + k];
#pragma unroll
        for (int off = 8; off; off >>= 1) p += __shfl_down(p, off, 16);
        if (j == 0) atomicAdd(&out[R + r], p + (dir ? 0.f : vsh_g[256]));
    }
}

extern "C" void kernel_launch(void* const* d_in, const int* in_sizes, int n_in,
                              void* d_out, int out_size, void* d_ws, size_t ws_size,
                              hipStream_t stream) {
    const float* x      = (const float*)d_in[0];
    const float* adjs   = (const float*)d_in[1];
    const float* win_w  = (const float*)d_in[3];
    const float* win_b  = (const float*)d_in[4];
    const float* fWx    = (const float*)d_in[5];
    const float* fWh    = (const float*)d_in[6];
    const float* fWn    = (const float*)d_in[7];
    const float* fb     = (const float*)d_in[8];
    const float* bWx    = (const float*)d_in[9];
    const float* bWh    = (const float*)d_in[10];
    const float* bWn    = (const float*)d_in[11];
    const float* bb     = (const float*)d_in[12];
    const float* fc0_w  = (const float*)d_in[13];
    const float* fc0_b  = (const float*)d_in[14];
    const float* wout_w = (const float*)d_in[15];
    const float* wout_b = (const float*)d_in[16];

    char* ws = (char*)d_ws;
    size_t off = 0;
    auto alloc = [&](size_t bytes) -> void* {
        void* p = ws + off;
        off += (bytes + 255) & ~(size_t)255;
        return p;
    };
    short* xs      = (short*)alloc((size_t)TS * NN * HH * 2);
    short* WcatT_f = (short*)alloc((size_t)H4 * KC * 2);
    short* WcatT_b = (short*)alloc((size_t)H4 * KC * 2);
    // 33-deep hT frame chains (write-once/read-once -> no stale-L2 hazard)
    short* hTf     = (short*)alloc((size_t)(TS + 1) * FRM * 2);
    short* hTb     = (short*)alloc((size_t)(TS + 1) * FRM * 2);
    float* vsh_g   = (float*)alloc(257 * 4);
    unsigned int* flags = (unsigned int*)alloc(512);
    float* outp    = (float*)d_out;

    hipLaunchKernelGGL(k_pre, dim3(609), dim3(256), 0, stream,
                       x, win_w, win_b, fWx, fWn, fWh, bWx, bWn, bWh,
                       fc0_w, fc0_b, wout_w, wout_b,
                       xs, hTf, hTb, WcatT_f, WcatT_b, vsh_g, flags, outp);

    void* args[] = {
        (void*)&adjs, (void*)&xs, (void*)&WcatT_f, (void*)&WcatT_b,
        (void*)&fb, (void*)&bb,
        (void*)&hTf, (void*)&hTb,
        (void*)&vsh_g, (void*)&flags, (void*)&outp,
    };
    hipLaunchCooperativeKernel((void*)k_main, dim3(128), dim3(512), args, 0, stream);
}